// Round 11
// baseline (390.208 us; speedup 1.0000x reference)
//
#include <hip/hip_runtime.h>
#include <math.h>

#define N0c   16
#define NAt   96
#define ORIG  92
#define Fc    64
#define Kc    41
#define Hc    128
#define NCc   3
#define C2    128   // 2F
#define EPSBN 1e-5f
#define JG    4
#define JPW   (NAt / JG)
#define NREP  32    // atomic replica slots
#define STS   88    // ST row stride (S at 0..40, pad 41..43, T at 44..84, pad)
#define INV1  (1.f / (float)(N0c * NAt * NAt))
#define INV2  (1.f / (float)(N0c * NAt))

__device__ __forceinline__ float sp_(float x){
    return fmaxf(x, 0.f) + __logf(1.f + __expf(-fabsf(x)));
}
__device__ __forceinline__ float sgm_(float x){
    return 1.f / (1.f + __expf(-x));
}

// fea = atom @ emb_W + emb_b
__global__ __launch_bounds__(256) void k_embed(const float* __restrict__ atom,
                                               const float* __restrict__ W,
                                               const float* __restrict__ b,
                                               float* __restrict__ fea){
    int row = blockIdx.x * 4 + (threadIdx.x >> 6);
    int f   = threadIdx.x & 63;
    const float* ar = atom + row * ORIG;
    float acc = b[f];
    #pragma unroll 4
    for (int o = 0; o < ORIG; ++o) acc += ar[o] * W[o * Fc + f];
    fea[row * Fc + f] = acc;
}

// One-time: S_r, T_r, cnt_r. ST rows padded to stride 88, pads zeroed.
__global__ __launch_bounds__(256) void k_pre(const float* __restrict__ nbr,
                                             const int*   __restrict__ adj,
                                             float* __restrict__ ST,
                                             float* __restrict__ cntf){
    int r    = blockIdx.x;
    int lane = threadIdx.x & 63;
    int jg   = __builtin_amdgcn_readfirstlane(threadIdx.x >> 6);
    __shared__ float rS[JG][Kc], rT[JG][Kc], rc[JG];
    float S = 0.f, T = 0.f, cn = 0.f;
    int j0 = jg * JPW;
    for (int j = j0; j < j0 + JPW; ++j){
        float a = (float)adj[r * NAt + j];
        float v = (lane < Kc) ? nbr[((size_t)r * NAt + j) * Kc + lane] : 0.f;
        S += v; T += a * v; cn += a;
    }
    if (lane < Kc){ rS[jg][lane] = S; rT[jg][lane] = T; }
    if (lane == 0) rc[jg] = cn;
    __syncthreads();
    int t = threadIdx.x;
    if (t < 44){
        float sv = (t < Kc) ? rS[0][t] + rS[1][t] + rS[2][t] + rS[3][t] : 0.f;
        float tv = (t < Kc) ? rT[0][t] + rT[1][t] + rT[2][t] + rT[3][t] : 0.f;
        ST[r * STS + t]      = sv;
        ST[r * STS + 44 + t] = tv;
    }
    if (t == 0) cntf[r] = rc[0] + rc[1] + rc[2] + rc[3];
}

// Gram partials: rpb r's per block, private partial per block (no atomics).
__global__ __launch_bounds__(128) void k_gram(const float* __restrict__ nbr,
                                              float* __restrict__ pG, int rpb){
    int blk = blockIdx.x;
    int t   = threadIdx.x;
    int k   = (t % 21) * 2;
    int lb  = (t / 21) * 7;
    __shared__ float L[NAt * Kc];                    // 15.7 KB
    float a0[7] = {0,0,0,0,0,0,0}, a1[7] = {0,0,0,0,0,0,0};
    for (int rr = 0; rr < rpb; ++rr){
        int r = blk * rpb + rr;
        __syncthreads();
        for (int i = t; i < NAt * Kc; i += 128)
            L[i] = nbr[(size_t)r * NAt * Kc + i];
        __syncthreads();
        if (t < 126){
            for (int j = 0; j < NAt; ++j){
                float vk0 = L[j * Kc + k];
                float vk1 = (k + 1 < Kc) ? L[j * Kc + k + 1] : 0.f;
                #pragma unroll
                for (int m = 0; m < 7; ++m){
                    if (lb + m < Kc){
                        float lv = L[j * Kc + lb + m];
                        a0[m] += vk0 * lv;
                        a1[m] += vk1 * lv;
                    }
                }
            }
        }
    }
    if (t < 126){
        float* dst = pG + (size_t)blk * (Kc * Kc);
        #pragma unroll
        for (int m = 0; m < 7; ++m){
            if (lb + m < Kc){
                dst[k * Kc + lb + m] = a0[m];
                if (k + 1 < Kc) dst[(k + 1) * Kc + lb + m] = a1[m];
            }
        }
    }
}

// Phased partial reduce.
__global__ __launch_bounds__(64) void k_gred(const float* __restrict__ pG,
                                             float* __restrict__ G){
    int i  = (blockIdx.x % 27) * 64 + threadIdx.x;
    int b0 = (blockIdx.x / 27) * 96;
    if (i < Kc * Kc){
        float s = 0.f;
        #pragma unroll 4
        for (int b = b0; b < b0 + 96; ++b) s += pG[(size_t)b * (Kc * Kc) + i];
        atomicAdd(&G[i], s);
    }
}

// One-time: transposed padded W3: W3T[l][c][44] (16B rows, zero pad)
__global__ void k_wt(const float* __restrict__ convW, float* __restrict__ W3T){
    int l = blockIdx.x, c = threadIdx.x;
    const float* Wl = convW + (size_t)l * 169 * C2;
    float* dst = W3T + ((size_t)l * C2 + c) * 44;
    for (int k = 0; k < Kc; ++k) dst[k] = Wl[(C2 + k) * C2 + c];
    dst[41] = 0.f; dst[42] = 0.f; dst[43] = 0.f;
}

// One-time: q3[l][c] = w3^T G w3
__global__ __launch_bounds__(128) void k_quad(const float* __restrict__ G,
                                              const float* __restrict__ convW,
                                              float* __restrict__ q3){
    int l = blockIdx.x, c = threadIdx.x;
    const float* Wl = convW + (size_t)l * 169 * C2;
    __shared__ float GL[Kc * Kc];
    for (int i = c; i < Kc * Kc; i += 128) GL[i] = G[i];
    float w3[Kc];
    #pragma unroll
    for (int k = 0; k < Kc; ++k) w3[k] = Wl[(C2 + k) * C2 + c];
    __syncthreads();
    float q = 0.f;
    for (int k = 0; k < Kc; ++k){
        float gw = 0.f;
        #pragma unroll
        for (int m = 0; m < Kc; ++m) gw += GL[k * Kc + m] * w3[m];
        q += w3[k] * gw;
    }
    q3[l * C2 + c] = q;
}

// Fused p12 + closed-form BN1 stats, one row per block. float2-packed dots
// (v_pk_fma_f32 target). ST stride 88 keeps both S/T halves 8B-aligned.
__global__ __launch_bounds__(128)
__attribute__((amdgpu_waves_per_eu(2, 4)))
void k_front(const float* __restrict__ fea,
             const float* __restrict__ Wl,
             const float* __restrict__ bl,
             const float* __restrict__ W3Tl,
             const float* __restrict__ ST,
             const float* __restrict__ cntf,
             float* __restrict__ p1,
             float* __restrict__ p2,
             float* __restrict__ sum1R,
             float* __restrict__ sq1R){
    int c = threadIdx.x;
    int r = blockIdx.x;
    float2 w32[22];
    const float2* wt2 = (const float2*)(W3Tl + c * 44);   // 8B-aligned
    #pragma unroll
    for (int k = 0; k < 22; ++k) w32[k] = wt2[k];
    const float* fr = fea + r * Fc;
    float2 a1v = make_float2(bl[c], 0.f), a2v = make_float2(0.f, 0.f);
    #pragma unroll 8
    for (int f = 0; f < Fc; f += 2){
        float fv0 = fr[f], fv1 = fr[f + 1];               // uniform s_loads
        a1v.x = fmaf(fv0, Wl[f * C2 + c],        a1v.x);
        a1v.y = fmaf(fv1, Wl[(f + 1) * C2 + c],  a1v.y);
        a2v.x = fmaf(fv0, Wl[(Fc + f) * C2 + c],     a2v.x);
        a2v.y = fmaf(fv1, Wl[(Fc + f + 1) * C2 + c], a2v.y);
    }
    float a1 = a1v.x + a1v.y, a2 = a2v.x + a2v.y;
    p1[r * C2 + c] = a1;
    p2[r * C2 + c] = a2;
    const float2* Sr2 = (const float2*)(ST + r * STS);    // uniform s_loads
    const float2* Tr2 = Sr2 + 22;
    float2 u2 = make_float2(0.f, 0.f), t2 = make_float2(0.f, 0.f);
    #pragma unroll
    for (int k = 0; k < 22; ++k){
        float2 s = Sr2[k], t = Tr2[k], w = w32[k];
        u2.x = fmaf(s.x, w.x, u2.x);  u2.y = fmaf(s.y, w.y, u2.y);
        t2.x = fmaf(t.x, w.x, t2.x);  t2.y = fmaf(t.y, w.y, t2.y);
    }
    float u = u2.x + u2.y, tt = t2.x + t2.y;
    float cn = cntf[r];
    float s1 = (float)NAt * a1 + cn * a2 + u;
    float q1 = (float)NAt * a1 * a1 + cn * a2 * a2
             + 2.f * cn * a1 * a2 + 2.f * a1 * u + 2.f * a2 * tt;
    int slot = blockIdx.x & (NREP - 1);
    atomicAdd(&sum1R[slot * C2 + c], s1);
    atomicAdd(&sq1R[slot * C2 + c], q1);
}

// Pass 2 v6: R9 shape (grid ROWS, 32 f-pairs/block — FETCH back to ~27 MB),
// float2-packed inner dot targeting v_pk_fma_f32 (halves FMA issue count).
__global__ __launch_bounds__(192)
__attribute__((amdgpu_waves_per_eu(2, 4)))
void k_apply(const float* __restrict__ nbr,
             const int*   __restrict__ adj,
             const float* __restrict__ w3t,
             const float* __restrict__ p1,
             const float* __restrict__ p2,
             const float* __restrict__ sum1R,
             const float* __restrict__ sq1R,
             const float* __restrict__ qv,
             const float* __restrict__ g1,
             const float* __restrict__ b1,
             float* __restrict__ summed,
             float* __restrict__ sum2R,
             float* __restrict__ sq2R){
    int tid = threadIdx.x;
    int fh  = blockIdx.x & 1;
    int pr  = blockIdx.x >> 1;
    int f0  = fh * 32;
    int bi0 = pr * 2;
    __shared__ float ABf[4][32];     // A1,B1,A2,B2
    __shared__ float PL[2][4][32];   // pa1,pa2,pb1,pb2 per bi
    __shared__ float Tp[6][32];      // halfgroup partials

    if (tid < 64){                   // fold BN1 finalize (replica reduce)
        int half = tid >> 5, fi = tid & 31;
        int c = half * 64 + f0 + fi;
        float s = 0.f, q = 0.f;
        for (int r = 0; r < NREP; ++r){ s += sum1R[r * C2 + c]; q += sq1R[r * C2 + c]; }
        float m = s * INV1;
        float v = (q + qv[c]) * INV1 - m * m;
        float A = g1[c] * rsqrtf(v + EPSBN);
        ABf[half * 2 + 0][fi] = A;
        ABf[half * 2 + 1][fi] = b1[c] - m * A;
    } else {                         // stage p1/p2 fragments
        int vv = tid - 64;
        #pragma unroll
        for (int h = 0; h < 2; ++h){
            int idx = vv + h * 128;
            int bl_ = idx >> 7, rem = idx & 127, arr = rem >> 5, fi = rem & 31;
            int r = bi0 + bl_;
            int c = ((arr & 2) ? 64 : 0) + f0 + fi;
            const float* src = (arr & 1) ? p2 : p1;
            PL[bl_][arr][fi] = src[r * C2 + c];
        }
    }
    int bi_l = (tid >= 96) ? 1 : 0;
    int j    = tid - bi_l * 96;
    int bi   = bi0 + bi_l;
    float ajf = (float)adj[bi * NAt + j];
    float2 nr2[21];                  // packed j-row; [20].y = 0 pad
    const float* nrow = nbr + ((size_t)bi * NAt + j) * Kc;
    #pragma unroll
    for (int k = 0; k < 20; ++k) nr2[k] = make_float2(nrow[2 * k], nrow[2 * k + 1]);
    nr2[20] = make_float2(nrow[40], 0.f);
    __syncthreads();

    int hg = tid >> 5;
    #pragma unroll 2
    for (int f = 0; f < 32; ++f){
        const float2* wA2 = (const float2*)(w3t + (f0 + f) * 44);      // uniform
        const float2* wB2 = (const float2*)(w3t + (64 + f0 + f) * 44); // uniform
        float2 dA = make_float2(0.f, 0.f), dB = make_float2(0.f, 0.f);
        #pragma unroll
        for (int k = 0; k < 21; ++k){
            float2 n = nr2[k];
            float2 wa = wA2[k], wb = wB2[k];   // W3T pad guarantees [20].y = 0
            dA.x = fmaf(n.x, wa.x, dA.x);  dA.y = fmaf(n.y, wa.y, dA.y);
            dB.x = fmaf(n.x, wb.x, dB.x);  dB.y = fmaf(n.y, wb.y, dB.y);
        }
        float d = dA.x + dA.y;
        float e = dB.x + dB.y;
        float gf = (PL[bi_l][0][f] + ajf * PL[bi_l][1][f] + d) * ABf[0][f] + ABf[1][f];
        float gc = (PL[bi_l][2][f] + ajf * PL[bi_l][3][f] + e) * ABf[2][f] + ABf[3][f];
        float t = sgm_(gf) * sp_(gc);
        t += __shfl_xor(t, 1);  t += __shfl_xor(t, 2);  t += __shfl_xor(t, 4);
        t += __shfl_xor(t, 8);  t += __shfl_xor(t, 16);
        if ((tid & 31) == 0) Tp[hg][f] = t;
    }
    __syncthreads();
    if (tid < 64){
        int bl_ = tid >> 5, fi = tid & 31;
        float s = Tp[bl_ * 3 + 0][fi] + Tp[bl_ * 3 + 1][fi] + Tp[bl_ * 3 + 2][fi];
        summed[(bi0 + bl_) * Fc + f0 + fi] = s;
        int slot = blockIdx.x & (NREP - 1);
        atomicAdd(&sum2R[slot * Fc + f0 + fi], s);
        atomicAdd(&sq2R[slot * Fc + f0 + fi], s * s);
    }
}

// fea = softplus(fea + BN2(summed)), BN2 finalize folded in.
__global__ __launch_bounds__(256) void k_update(float* __restrict__ fea,
                                                const float* __restrict__ summed,
                                                const float* __restrict__ sum2R,
                                                const float* __restrict__ sq2R,
                                                const float* __restrict__ g2,
                                                const float* __restrict__ b2){
    __shared__ float A2L[Fc], B2L[Fc];
    int tid = threadIdx.x;
    if (tid < Fc){
        float s = 0.f, q = 0.f;
        for (int r = 0; r < NREP; ++r){ s += sum2R[r * Fc + tid]; q += sq2R[r * Fc + tid]; }
        float m = s * INV2;
        float v = q * INV2 - m * m;
        float A = g2[tid] * rsqrtf(v + EPSBN);
        A2L[tid] = A;
        B2L[tid] = b2[tid] - m * A;
    }
    __syncthreads();
    int idx = blockIdx.x * 256 + tid;
    int f   = idx & 63;
    fea[idx] = sp_(fea[idx] + summed[idx] * A2L[f] + B2L[f]);
}

// crys = mean_i fea; out = softplus(softplus(crys)@fcW + fcb) @ outW + outb
__global__ __launch_bounds__(128) void k_final(const float* __restrict__ fea,
                                               const float* __restrict__ fcW,
                                               const float* __restrict__ fcb,
                                               const float* __restrict__ outW,
                                               const float* __restrict__ outb,
                                               float* __restrict__ out){
    int b = blockIdx.x;
    int t = threadIdx.x;
    __shared__ float spc[Fc];
    __shared__ float red[Hc];
    if (t < Fc){
        float s = 0.f;
        for (int i = 0; i < NAt; ++i) s += fea[(b * NAt + i) * Fc + t];
        spc[t] = sp_(s * (1.f / NAt));
    }
    __syncthreads();
    float h = fcb[t];
    #pragma unroll 4
    for (int f = 0; f < Fc; ++f) h += spc[f] * fcW[f * Hc + t];
    h = sp_(h);
    red[t] = h * outW[t];
    __syncthreads();
    for (int off = 64; off > 0; off >>= 1){
        if (t < off) red[t] += red[t + off];
        __syncthreads();
    }
    if (t == 0) out[b] = red[0] + outb[0];
}

extern "C" void kernel_launch(void* const* d_in, const int* in_sizes, int n_in,
                              void* d_out, int out_size, void* d_ws, size_t ws_size,
                              hipStream_t stream){
    const float* atom  = (const float*)d_in[0];
    const float* nbr   = (const float*)d_in[1];
    const int*   adj   = (const int*)  d_in[2];
    const float* embW  = (const float*)d_in[3];
    const float* embB  = (const float*)d_in[4];
    const float* convW = (const float*)d_in[5];
    const float* convB = (const float*)d_in[6];
    const float* bn1g  = (const float*)d_in[7];
    const float* bn1b  = (const float*)d_in[8];
    const float* bn2g  = (const float*)d_in[9];
    const float* bn2b  = (const float*)d_in[10];
    const float* fcW   = (const float*)d_in[11];
    const float* fcb   = (const float*)d_in[12];
    const float* outW  = (const float*)d_in[13];
    const float* outb  = (const float*)d_in[14];
    float* out = (float*)d_out;
    float* ws  = (float*)d_ws;

    const int ROWS = N0c * NAt;            // 1536
    float* fea    = ws;                    // 98304
    float* p1     = ws + 98304;            // 196608
    float* p2     = ws + 294912;           // 196608
    float* summed = ws + 491520;           // 98304
    float* SR     = ws + 589824;           // 12288 replica stats
    float* sum1R = SR;          float* sq1R = SR + 4096;
    float* sum2R = SR + 8192;   float* sq2R = SR + 10240;
    float* ST     = ws + 602112;           // 1536*88 = 135168
    float* cntf   = ws + 737280;           // 1536
    float* q3     = ws + 738816;           // 384
    float* W3T    = ws + 739200;           // 16896 -> PERS end 756096
    const size_t PERS = 756096;

    size_t ws_f = ws_size / sizeof(float);
    int nblk; float *pG, *G;
    if (ws_f >= PERS + (size_t)1536 * 1681 + 1681 + 64){
        nblk = 1536; pG = ws + PERS; G = pG + (size_t)nblk * 1681;
    } else if (ws_f >= PERS + (size_t)768 * 1681 + 1681 + 64){
        nblk = 768;  pG = ws + PERS; G = pG + (size_t)nblk * 1681;
    } else if (ws_f >= PERS + (size_t)384 * 1681 + 1681 + 64){
        nblk = 384;  pG = ws + PERS; G = pG + (size_t)nblk * 1681;
    } else {
        nblk = 384;  pG = ws;        G = ws + 650000;
    }
    int rpb = 1536 / nblk;
    int ph  = nblk / 96;

    hipMemsetAsync(G, 0, Kc * Kc * sizeof(float), stream);
    k_gram <<<nblk, 128, 0, stream>>>(nbr, pG, rpb);
    k_gred <<<27 * ph, 64, 0, stream>>>(pG, G);
    k_wt   <<<NCc, C2, 0, stream>>>(convW, W3T);
    k_quad <<<NCc, C2, 0, stream>>>(G, convW, q3);
    k_embed<<<ROWS / 4, 256, 0, stream>>>(atom, embW, embB, fea);
    k_pre  <<<ROWS, 256, 0, stream>>>(nbr, adj, ST, cntf);

    for (int l = 0; l < NCc; ++l){
        const float* Wl   = convW + (size_t)l * 169 * C2;
        const float* bl   = convB + l * C2;
        const float* W3Tl = W3T + (size_t)l * C2 * 44;
        hipMemsetAsync(SR, 0, 12288 * sizeof(float), stream);
        k_front <<<ROWS, C2, 0, stream>>>(fea, Wl, bl, W3Tl, ST, cntf,
                                          p1, p2, sum1R, sq1R);
        k_apply <<<ROWS, 192, 0, stream>>>(nbr, adj, W3Tl, p1, p2,
                                           sum1R, sq1R, q3 + l * C2,
                                           bn1g + l * C2, bn1b + l * C2,
                                           summed, sum2R, sq2R);
        k_update<<<ROWS * Fc / 256, 256, 0, stream>>>(fea, summed, sum2R, sq2R,
                                                      bn2g + l * Fc, bn2b + l * Fc);
    }

    k_final<<<N0c, Hc, 0, stream>>>(fea, fcW, fcb, outW, outb, out);
}

// Round 12
// 335.739 us; speedup vs baseline: 1.1622x; 1.1622x over previous
//
#include <hip/hip_runtime.h>
#include <math.h>

#define N0c   16
#define NAt   96
#define ORIG  92
#define Fc    64
#define Kc    41
#define Hc    128
#define NCc   3
#define C2    128   // 2F
#define EPSBN 1e-5f
#define JG    4
#define JPW   (NAt / JG)
#define NREP  32    // atomic replica slots
#define SRL_STRIDE 12288   // per-layer replica block
#define INV1  (1.f / (float)(N0c * NAt * NAt))
#define INV2  (1.f / (float)(N0c * NAt))

__device__ __forceinline__ float sp_(float x){
    return fmaxf(x, 0.f) + __logf(1.f + __expf(-fabsf(x)));
}
__device__ __forceinline__ float sgm_(float x){
    return 1.f / (1.f + __expf(-x));
}

// fea = atom @ emb_W + emb_b
__global__ __launch_bounds__(256) void k_embed(const float* __restrict__ atom,
                                               const float* __restrict__ W,
                                               const float* __restrict__ b,
                                               float* __restrict__ fea){
    int row = blockIdx.x * 4 + (threadIdx.x >> 6);
    int f   = threadIdx.x & 63;
    const float* ar = atom + row * ORIG;
    float acc = b[f];
    #pragma unroll 4
    for (int o = 0; o < ORIG; ++o) acc += ar[o] * W[o * Fc + f];
    fea[row * Fc + f] = acc;
}

// One-time: S_r, T_r, cnt_r.  (identical to R9)
__global__ __launch_bounds__(256) void k_pre(const float* __restrict__ nbr,
                                             const int*   __restrict__ adj,
                                             float* __restrict__ ST,
                                             float* __restrict__ cntf){
    int r    = blockIdx.x;
    int lane = threadIdx.x & 63;
    int jg   = __builtin_amdgcn_readfirstlane(threadIdx.x >> 6);
    __shared__ float rS[JG][Kc], rT[JG][Kc], rc[JG];
    float S = 0.f, T = 0.f, cn = 0.f;
    int j0 = jg * JPW;
    for (int j = j0; j < j0 + JPW; ++j){
        float a = (float)adj[r * NAt + j];
        float v = (lane < Kc) ? nbr[((size_t)r * NAt + j) * Kc + lane] : 0.f;
        S += v; T += a * v; cn += a;
    }
    if (lane < Kc){ rS[jg][lane] = S; rT[jg][lane] = T; }
    if (lane == 0) rc[jg] = cn;
    __syncthreads();
    int t = threadIdx.x;
    if (t < Kc){
        ST[r * (2 * Kc) + t]      = rS[0][t] + rS[1][t] + rS[2][t] + rS[3][t];
        ST[r * (2 * Kc) + Kc + t] = rT[0][t] + rT[1][t] + rT[2][t] + rT[3][t];
    }
    if (t == 0) cntf[r] = rc[0] + rc[1] + rc[2] + rc[3];
}

// Gram partials (identical to R9).
__global__ __launch_bounds__(128) void k_gram(const float* __restrict__ nbr,
                                              float* __restrict__ pG, int rpb){
    int blk = blockIdx.x;
    int t   = threadIdx.x;
    int k   = (t % 21) * 2;
    int lb  = (t / 21) * 7;
    __shared__ float L[NAt * Kc];                    // 15.7 KB
    float a0[7] = {0,0,0,0,0,0,0}, a1[7] = {0,0,0,0,0,0,0};
    for (int rr = 0; rr < rpb; ++rr){
        int r = blk * rpb + rr;
        __syncthreads();
        for (int i = t; i < NAt * Kc; i += 128)
            L[i] = nbr[(size_t)r * NAt * Kc + i];
        __syncthreads();
        if (t < 126){
            for (int j = 0; j < NAt; ++j){
                float vk0 = L[j * Kc + k];
                float vk1 = (k + 1 < Kc) ? L[j * Kc + k + 1] : 0.f;
                #pragma unroll
                for (int m = 0; m < 7; ++m){
                    if (lb + m < Kc){
                        float lv = L[j * Kc + lb + m];
                        a0[m] += vk0 * lv;
                        a1[m] += vk1 * lv;
                    }
                }
            }
        }
    }
    if (t < 126){
        float* dst = pG + (size_t)blk * (Kc * Kc);
        #pragma unroll
        for (int m = 0; m < 7; ++m){
            if (lb + m < Kc){
                dst[k * Kc + lb + m] = a0[m];
                if (k + 1 < Kc) dst[(k + 1) * Kc + lb + m] = a1[m];
            }
        }
    }
}

// Phased partial reduce (identical to R9).
__global__ __launch_bounds__(64) void k_gred(const float* __restrict__ pG,
                                             float* __restrict__ G){
    int i  = (blockIdx.x % 27) * 64 + threadIdx.x;
    int b0 = (blockIdx.x / 27) * 96;
    if (i < Kc * Kc){
        float s = 0.f;
        #pragma unroll 4
        for (int b = b0; b < b0 + 96; ++b) s += pG[(size_t)b * (Kc * Kc) + i];
        atomicAdd(&G[i], s);
    }
}

// One-time: transposed padded W3: W3T[l][c][44]
__global__ void k_wt(const float* __restrict__ convW, float* __restrict__ W3T){
    int l = blockIdx.x, c = threadIdx.x;
    const float* Wl = convW + (size_t)l * 169 * C2;
    float* dst = W3T + ((size_t)l * C2 + c) * 44;
    for (int k = 0; k < Kc; ++k) dst[k] = Wl[(C2 + k) * C2 + c];
    dst[41] = 0.f; dst[42] = 0.f; dst[43] = 0.f;
}

// One-time: q3[l][c] = w3^T G w3
__global__ __launch_bounds__(128) void k_quad(const float* __restrict__ G,
                                              const float* __restrict__ convW,
                                              float* __restrict__ q3){
    int l = blockIdx.x, c = threadIdx.x;
    const float* Wl = convW + (size_t)l * 169 * C2;
    __shared__ float GL[Kc * Kc];
    for (int i = c; i < Kc * Kc; i += 128) GL[i] = G[i];
    float w3[Kc];
    #pragma unroll
    for (int k = 0; k < Kc; ++k) w3[k] = Wl[(C2 + k) * C2 + c];
    __syncthreads();
    float q = 0.f;
    for (int k = 0; k < Kc; ++k){
        float gw = 0.f;
        #pragma unroll
        for (int m = 0; m < Kc; ++m) gw += GL[k * Kc + m] * w3[m];
        q += w3[k] * gw;
    }
    q3[l * C2 + c] = q;
}

// Fused: [BN2-update of previous layer] + p12 + closed-form BN1 stats.
// 2 rows per block, 128 threads. upd=0 for layer 0.
__global__ __launch_bounds__(128)
void k_front(float* __restrict__ fea,
             const float* __restrict__ Wl,
             const float* __restrict__ bl,
             const float* __restrict__ W3Tl,
             const float* __restrict__ ST,
             const float* __restrict__ cntf,
             float* __restrict__ p1,
             float* __restrict__ p2,
             float* __restrict__ sum1R,
             float* __restrict__ sq1R,
             const float* __restrict__ summed,
             const float* __restrict__ sum2Rp,
             const float* __restrict__ sq2Rp,
             const float* __restrict__ g2p,
             const float* __restrict__ b2p,
             int upd){
    int c  = threadIdx.x;
    int r0 = blockIdx.x * 2;
    __shared__ float F2[2][Fc];
    __shared__ float A2L[Fc], B2L[Fc];

    if (upd){
        if (c < Fc){
            float s = 0.f, q = 0.f;
            for (int rr = 0; rr < NREP; ++rr){
                s += sum2Rp[rr * Fc + c];
                q += sq2Rp[rr * Fc + c];
            }
            float m = s * INV2;
            float v = q * INV2 - m * m;
            float A = g2p[c] * rsqrtf(v + EPSBN);
            A2L[c] = A;
            B2L[c] = b2p[c] - m * A;
        }
        __syncthreads();
        {
            int rr = c >> 6, cc = c & 63;
            int r  = r0 + rr;
            float nv = sp_(fea[r * Fc + cc] + summed[r * Fc + cc] * A2L[cc] + B2L[cc]);
            F2[rr][cc] = nv;
            fea[r * Fc + cc] = nv;       // persist for next front / k_final path
        }
        __syncthreads();
    } else {
        int rr = c >> 6, cc = c & 63;
        F2[rr][cc] = fea[(r0 + rr) * Fc + cc];
        __syncthreads();
    }

    float w3[Kc];
    const float* wt = W3Tl + c * 44;       // per-lane contiguous -> float4 loads
    #pragma unroll
    for (int k = 0; k < 40; k += 4){
        float4 v = *(const float4*)(wt + k);
        w3[k] = v.x; w3[k+1] = v.y; w3[k+2] = v.z; w3[k+3] = v.w;
    }
    w3[40] = wt[40];
    float s1 = 0.f, q1 = 0.f;
    for (int rr = 0; rr < 2; ++rr){
        int r = r0 + rr;
        float a1 = bl[c], a2 = 0.f;
        #pragma unroll 8
        for (int f = 0; f < Fc; ++f){
            float fv = F2[rr][f];          // LDS broadcast
            a1 += fv * Wl[f * C2 + c];
            a2 += fv * Wl[(Fc + f) * C2 + c];
        }
        p1[r * C2 + c] = a1;
        p2[r * C2 + c] = a2;
        const float* Sr = ST + r * (2 * Kc);   // uniform -> s_loads
        const float* Tr = Sr + Kc;
        float u = 0.f, tt = 0.f;
        #pragma unroll
        for (int k = 0; k < Kc; ++k){ u += Sr[k] * w3[k]; tt += Tr[k] * w3[k]; }
        float cn = cntf[r];
        s1 += (float)NAt * a1 + cn * a2 + u;
        q1 += (float)NAt * a1 * a1 + cn * a2 * a2
            + 2.f * cn * a1 * a2 + 2.f * a1 * u + 2.f * a2 * tt;
    }
    int slot = blockIdx.x & (NREP - 1);
    atomicAdd(&sum1R[slot * C2 + c], s1);
    atomicAdd(&sq1R[slot * C2 + c], q1);
}

// Pass 2 (EXACT R9 v4 — proven 50.6 us): thread owns one j-row (nr[41]),
// loops channels; weights via wave-uniform s_loads from W3T.
__global__ __launch_bounds__(192, 2) void k_apply(const float* __restrict__ nbr,
                                                  const int*   __restrict__ adj,
                                                  const float* __restrict__ w3t,
                                                  const float* __restrict__ p1,
                                                  const float* __restrict__ p2,
                                                  const float* __restrict__ sum1R,
                                                  const float* __restrict__ sq1R,
                                                  const float* __restrict__ qv,
                                                  const float* __restrict__ g1,
                                                  const float* __restrict__ b1,
                                                  float* __restrict__ summed,
                                                  float* __restrict__ sum2R,
                                                  float* __restrict__ sq2R){
    int tid = threadIdx.x;
    int fh  = blockIdx.x & 1;
    int pr  = blockIdx.x >> 1;
    int f0  = fh * 32;
    int bi0 = pr * 2;
    __shared__ float ABf[4][32];     // A1,B1,A2,B2
    __shared__ float PL[2][4][32];   // pa1,pa2,pb1,pb2 per bi
    __shared__ float Tp[6][32];      // halfgroup partials

    if (tid < 64){                   // fold BN1 finalize (replica reduce)
        int half = tid >> 5, fi = tid & 31;
        int c = half * 64 + f0 + fi;
        float s = 0.f, q = 0.f;
        for (int r = 0; r < NREP; ++r){ s += sum1R[r * C2 + c]; q += sq1R[r * C2 + c]; }
        float m = s * INV1;
        float v = (q + qv[c]) * INV1 - m * m;
        float A = g1[c] * rsqrtf(v + EPSBN);
        ABf[half * 2 + 0][fi] = A;
        ABf[half * 2 + 1][fi] = b1[c] - m * A;
    } else {                         // stage p1/p2 fragments
        int vv = tid - 64;
        #pragma unroll
        for (int h = 0; h < 2; ++h){
            int idx = vv + h * 128;
            int bl_ = idx >> 7, rem = idx & 127, arr = rem >> 5, fi = rem & 31;
            int r = bi0 + bl_;
            int c = ((arr & 2) ? 64 : 0) + f0 + fi;
            const float* src = (arr & 1) ? p2 : p1;
            PL[bl_][arr][fi] = src[r * C2 + c];
        }
    }
    int bi_l = (tid >= 96) ? 1 : 0;
    int j    = tid - bi_l * 96;
    int bi   = bi0 + bi_l;
    float ajf = (float)adj[bi * NAt + j];
    float nr[Kc];
    const float* nrow = nbr + ((size_t)bi * NAt + j) * Kc;
    #pragma unroll
    for (int k = 0; k < Kc; ++k) nr[k] = nrow[k];
    __syncthreads();

    int hg = tid >> 5;
    #pragma unroll 2
    for (int f = 0; f < 32; ++f){
        const float* wA = w3t + (f0 + f) * 44;        // uniform -> s_loads
        const float* wB = w3t + (64 + f0 + f) * 44;
        float d0 = 0.f, d1 = 0.f, e0 = 0.f, e1 = 0.f;
        #pragma unroll
        for (int k = 0; k < 40; k += 2){
            d0 += nr[k] * wA[k];     d1 += nr[k+1] * wA[k+1];
            e0 += nr[k] * wB[k];     e1 += nr[k+1] * wB[k+1];
        }
        d0 += nr[40] * wA[40];
        e0 += nr[40] * wB[40];
        float gf = (PL[bi_l][0][f] + ajf * PL[bi_l][1][f] + (d0 + d1)) * ABf[0][f] + ABf[1][f];
        float gc = (PL[bi_l][2][f] + ajf * PL[bi_l][3][f] + (e0 + e1)) * ABf[2][f] + ABf[3][f];
        float t = sgm_(gf) * sp_(gc);
        t += __shfl_xor(t, 1);  t += __shfl_xor(t, 2);  t += __shfl_xor(t, 4);
        t += __shfl_xor(t, 8);  t += __shfl_xor(t, 16);
        if ((tid & 31) == 0) Tp[hg][f] = t;
    }
    __syncthreads();
    if (tid < 64){
        int bl_ = tid >> 5, fi = tid & 31;
        float s = Tp[bl_ * 3 + 0][fi] + Tp[bl_ * 3 + 1][fi] + Tp[bl_ * 3 + 2][fi];
        summed[(bi0 + bl_) * Fc + f0 + fi] = s;
        int slot = blockIdx.x & (NREP - 1);
        atomicAdd(&sum2R[slot * Fc + f0 + fi], s);
        atomicAdd(&sq2R[slot * Fc + f0 + fi], s * s);
    }
}

// Tail: apply layer-2 BN2 update inline, mean over i, fc, out.
__global__ __launch_bounds__(128) void k_final(const float* __restrict__ fea,
                                               const float* __restrict__ summed,
                                               const float* __restrict__ sum2R,
                                               const float* __restrict__ sq2R,
                                               const float* __restrict__ g2,
                                               const float* __restrict__ b2,
                                               const float* __restrict__ fcW,
                                               const float* __restrict__ fcb,
                                               const float* __restrict__ outW,
                                               const float* __restrict__ outb,
                                               float* __restrict__ out){
    int b = blockIdx.x;
    int t = threadIdx.x;
    __shared__ float spc[Fc];
    __shared__ float red[Hc];
    if (t < Fc){
        float s = 0.f, q = 0.f;
        for (int r = 0; r < NREP; ++r){ s += sum2R[r * Fc + t]; q += sq2R[r * Fc + t]; }
        float m  = s * INV2;
        float v  = q * INV2 - m * m;
        float A2 = g2[t] * rsqrtf(v + EPSBN);
        float B2 = b2[t] - m * A2;
        float acc = 0.f;
        for (int i = 0; i < NAt; ++i){
            int idx = (b * NAt + i) * Fc + t;
            acc += sp_(fea[idx] + summed[idx] * A2 + B2);
        }
        spc[t] = sp_(acc * (1.f / NAt));
    }
    __syncthreads();
    float h = fcb[t];
    #pragma unroll 4
    for (int f = 0; f < Fc; ++f) h += spc[f] * fcW[f * Hc + t];
    h = sp_(h);
    red[t] = h * outW[t];
    __syncthreads();
    for (int off = 64; off > 0; off >>= 1){
        if (t < off) red[t] += red[t + off];
        __syncthreads();
    }
    if (t == 0) out[b] = red[0] + outb[0];
}

extern "C" void kernel_launch(void* const* d_in, const int* in_sizes, int n_in,
                              void* d_out, int out_size, void* d_ws, size_t ws_size,
                              hipStream_t stream){
    const float* atom  = (const float*)d_in[0];
    const float* nbr   = (const float*)d_in[1];
    const int*   adj   = (const int*)  d_in[2];
    const float* embW  = (const float*)d_in[3];
    const float* embB  = (const float*)d_in[4];
    const float* convW = (const float*)d_in[5];
    const float* convB = (const float*)d_in[6];
    const float* bn1g  = (const float*)d_in[7];
    const float* bn1b  = (const float*)d_in[8];
    const float* bn2g  = (const float*)d_in[9];
    const float* bn2b  = (const float*)d_in[10];
    const float* fcW   = (const float*)d_in[11];
    const float* fcb   = (const float*)d_in[12];
    const float* outW  = (const float*)d_in[13];
    const float* outb  = (const float*)d_in[14];
    float* out = (float*)d_out;
    float* ws  = (float*)d_ws;

    const int ROWS = N0c * NAt;            // 1536
    float* fea    = ws;                    // 98304
    float* p1     = ws + 98304;            // 196608
    float* p2     = ws + 294912;           // 196608
    float* summed = ws + 491520;           // 98304
    float* SRL    = ws + 589824;           // 3 * 12288 per-layer replica stats
    float* ST     = ws + 626688;           // 1536*82 = 125952
    float* cntf   = ws + 752640;           // 1536
    float* q3     = ws + 754176;           // 384
    float* W3T    = ws + 754560;           // 16896 -> PERS end 771456
    const size_t PERS = 771456;

    size_t ws_f = ws_size / sizeof(float);
    int nblk; float *pG, *G;
    if (ws_f >= PERS + (size_t)1536 * 1681 + 1681 + 64){
        nblk = 1536; pG = ws + PERS; G = pG + (size_t)nblk * 1681;
    } else if (ws_f >= PERS + (size_t)768 * 1681 + 1681 + 64){
        nblk = 768;  pG = ws + PERS; G = pG + (size_t)nblk * 1681;
    } else if (ws_f >= PERS + (size_t)384 * 1681 + 1681 + 64){
        nblk = 384;  pG = ws + PERS; G = pG + (size_t)nblk * 1681;
    } else {
        // compact overlay: pG (384*1681=645504) over fea..SRL (dead until
        // k_embed / first memset below, both AFTER k_gred); G inside ST
        // region (written by k_pre AFTER k_quad consumed G).
        nblk = 384;  pG = ws;        G = ws + 650000;
    }
    int rpb = 1536 / nblk;
    int ph  = nblk / 96;

    hipMemsetAsync(G, 0, Kc * Kc * sizeof(float), stream);
    k_gram <<<nblk, 128, 0, stream>>>(nbr, pG, rpb);
    k_gred <<<27 * ph, 64, 0, stream>>>(pG, G);
    k_wt   <<<NCc, C2, 0, stream>>>(convW, W3T);
    k_quad <<<NCc, C2, 0, stream>>>(G, convW, q3);
    k_embed<<<ROWS / 4, 256, 0, stream>>>(atom, embW, embB, fea);
    k_pre  <<<ROWS, 256, 0, stream>>>(nbr, adj, ST, cntf);
    hipMemsetAsync(SRL, 0, 3 * SRL_STRIDE * sizeof(float), stream);  // all layers

    for (int l = 0; l < NCc; ++l){
        const float* Wl   = convW + (size_t)l * 169 * C2;
        const float* bl   = convB + l * C2;
        const float* W3Tl = W3T + (size_t)l * C2 * 44;
        float* sum1R = SRL + l * SRL_STRIDE;
        float* sq1R  = sum1R + 4096;
        float* sum2R = sum1R + 8192;
        float* sq2R  = sum1R + 10240;
        // previous layer's BN2 replicas (for the fused update in k_front)
        const float* sum2Rp = (l > 0) ? SRL + (l - 1) * SRL_STRIDE + 8192 : SRL;
        const float* sq2Rp  = (l > 0) ? SRL + (l - 1) * SRL_STRIDE + 10240 : SRL;
        const float* g2p    = bn2g + (l > 0 ? (l - 1) : 0) * Fc;
        const float* b2p    = bn2b + (l > 0 ? (l - 1) : 0) * Fc;

        k_front <<<ROWS / 2, C2, 0, stream>>>(fea, Wl, bl, W3Tl, ST, cntf,
                                              p1, p2, sum1R, sq1R,
                                              summed, sum2Rp, sq2Rp, g2p, b2p,
                                              l > 0 ? 1 : 0);
        k_apply <<<ROWS, 192, 0, stream>>>(nbr, adj, W3Tl, p1, p2,
                                           sum1R, sq1R, q3 + l * C2,
                                           bn1g + l * C2, bn1b + l * C2,
                                           summed, sum2R, sq2R);
    }

    k_final<<<N0c, Hc, 0, stream>>>(fea, summed,
                                    SRL + 2 * SRL_STRIDE + 8192,
                                    SRL + 2 * SRL_STRIDE + 10240,
                                    bn2g + 2 * Fc, bn2b + 2 * Fc,
                                    fcW, fcb, outW, outb, out);
}

// Round 13
// 292.636 us; speedup vs baseline: 1.3334x; 1.1473x over previous
//
#include <hip/hip_runtime.h>
#include <math.h>

#define N0c   16
#define NAt   96
#define ORIG  92
#define Fc    64
#define Kc    41
#define Hc    128
#define NCc   3
#define C2    128   // 2F
#define EPSBN 1e-5f
#define JG    4
#define JPW   (NAt / JG)
#define NREP  32    // atomic replica slots
#define SRL_STRIDE 12288   // per-layer replica block
#define AROW  72    // LDS A row stride in ushorts (16B-aligned rows)
#define WFRAG 16384 // ushorts per layer in W3F (8nt*2ks*2hl*64lane*8)
#define INV1  (1.f / (float)(N0c * NAt * NAt))
#define INV2  (1.f / (float)(N0c * NAt))

typedef __attribute__((ext_vector_type(8))) short short8_t;   // 8 bf16
typedef __attribute__((ext_vector_type(4))) float f32x4;

__device__ __forceinline__ float sp_(float x){
    return fmaxf(x, 0.f) + __logf(1.f + __expf(-fabsf(x)));
}
__device__ __forceinline__ float sgm_(float x){
    return 1.f / (1.f + __expf(-x));
}
__device__ __forceinline__ unsigned short bfhi(float x){
    union { float f; unsigned u; } v; v.f = x;
    unsigned r = v.u + 0x7fff + ((v.u >> 16) & 1);   // RNE to bf16
    return (unsigned short)(r >> 16);
}
__device__ __forceinline__ float bf2f(unsigned short h){
    union { float f; unsigned u; } v; v.u = ((unsigned)h) << 16; return v.f;
}

// fea = atom @ emb_W + emb_b
__global__ __launch_bounds__(256) void k_embed(const float* __restrict__ atom,
                                               const float* __restrict__ W,
                                               const float* __restrict__ b,
                                               float* __restrict__ fea){
    int row = blockIdx.x * 4 + (threadIdx.x >> 6);
    int f   = threadIdx.x & 63;
    const float* ar = atom + row * ORIG;
    float acc = b[f];
    #pragma unroll 4
    for (int o = 0; o < ORIG; ++o) acc += ar[o] * W[o * Fc + f];
    fea[row * Fc + f] = acc;
}

// One-time: S_r, T_r, cnt_r.
__global__ __launch_bounds__(256) void k_pre(const float* __restrict__ nbr,
                                             const int*   __restrict__ adj,
                                             float* __restrict__ ST,
                                             float* __restrict__ cntf){
    int r    = blockIdx.x;
    int lane = threadIdx.x & 63;
    int jg   = __builtin_amdgcn_readfirstlane(threadIdx.x >> 6);
    __shared__ float rS[JG][Kc], rT[JG][Kc], rc[JG];
    float S = 0.f, T = 0.f, cn = 0.f;
    int j0 = jg * JPW;
    for (int j = j0; j < j0 + JPW; ++j){
        float a = (float)adj[r * NAt + j];
        float v = (lane < Kc) ? nbr[((size_t)r * NAt + j) * Kc + lane] : 0.f;
        S += v; T += a * v; cn += a;
    }
    if (lane < Kc){ rS[jg][lane] = S; rT[jg][lane] = T; }
    if (lane == 0) rc[jg] = cn;
    __syncthreads();
    int t = threadIdx.x;
    if (t < Kc){
        ST[r * (2 * Kc) + t]      = rS[0][t] + rS[1][t] + rS[2][t] + rS[3][t];
        ST[r * (2 * Kc) + Kc + t] = rT[0][t] + rT[1][t] + rT[2][t] + rT[3][t];
    }
    if (t == 0) cntf[r] = rc[0] + rc[1] + rc[2] + rc[3];
}

// Gram partials (identical to R12).
__global__ __launch_bounds__(128) void k_gram(const float* __restrict__ nbr,
                                              float* __restrict__ pG, int rpb){
    int blk = blockIdx.x;
    int t   = threadIdx.x;
    int k   = (t % 21) * 2;
    int lb  = (t / 21) * 7;
    __shared__ float L[NAt * Kc];
    float a0[7] = {0,0,0,0,0,0,0}, a1[7] = {0,0,0,0,0,0,0};
    for (int rr = 0; rr < rpb; ++rr){
        int r = blk * rpb + rr;
        __syncthreads();
        for (int i = t; i < NAt * Kc; i += 128)
            L[i] = nbr[(size_t)r * NAt * Kc + i];
        __syncthreads();
        if (t < 126){
            for (int j = 0; j < NAt; ++j){
                float vk0 = L[j * Kc + k];
                float vk1 = (k + 1 < Kc) ? L[j * Kc + k + 1] : 0.f;
                #pragma unroll
                for (int m = 0; m < 7; ++m){
                    if (lb + m < Kc){
                        float lv = L[j * Kc + lb + m];
                        a0[m] += vk0 * lv;
                        a1[m] += vk1 * lv;
                    }
                }
            }
        }
    }
    if (t < 126){
        float* dst = pG + (size_t)blk * (Kc * Kc);
        #pragma unroll
        for (int m = 0; m < 7; ++m){
            if (lb + m < Kc){
                dst[k * Kc + lb + m] = a0[m];
                if (k + 1 < Kc) dst[(k + 1) * Kc + lb + m] = a1[m];
            }
        }
    }
}

__global__ __launch_bounds__(64) void k_gred(const float* __restrict__ pG,
                                             float* __restrict__ G){
    int i  = (blockIdx.x % 27) * 64 + threadIdx.x;
    int b0 = (blockIdx.x / 27) * 96;
    if (i < Kc * Kc){
        float s = 0.f;
        #pragma unroll 4
        for (int b = b0; b < b0 + 96; ++b) s += pG[(size_t)b * (Kc * Kc) + i];
        atomicAdd(&G[i], s);
    }
}

// One-time: transposed padded W3 float (for k_front): W3T[l][c][44]
__global__ void k_wt(const float* __restrict__ convW, float* __restrict__ W3T){
    int l = blockIdx.x, c = threadIdx.x;
    const float* Wl = convW + (size_t)l * 169 * C2;
    float* dst = W3T + ((size_t)l * C2 + c) * 44;
    for (int k = 0; k < Kc; ++k) dst[k] = Wl[(C2 + k) * C2 + c];
    dst[41] = 0.f; dst[42] = 0.f; dst[43] = 0.f;
}

// One-time: B-fragments in MFMA order, bf16 hi/lo, K zero-padded to 64.
// W3F[l][fid = (nt*2+ks)*2+h][lane][i], i<8: B[k = ks*32+(lane>>4)*8+i][n = nt*16+(lane&15)]
__global__ __launch_bounds__(256) void k_wtb(const float* __restrict__ convW,
                                             unsigned short* __restrict__ W3F){
    int l = blockIdx.x;
    const float* Wl = convW + (size_t)l * 169 * C2;
    for (int it = 0; it < 8; ++it){
        int idx  = threadIdx.x + it * 256;        // [0,2048)
        int lane = idx & 63;
        int fid  = idx >> 6;                      // [0,32)
        int h    = fid & 1;
        int ks   = (fid >> 1) & 1;
        int nt   = fid >> 2;
        int n    = nt * 16 + (lane & 15);
        unsigned short* dst = W3F + (size_t)l * WFRAG + fid * 512 + lane * 8;
        #pragma unroll
        for (int i = 0; i < 8; ++i){
            int k = ks * 32 + (lane >> 4) * 8 + i;
            float w = (k < Kc) ? Wl[(C2 + k) * C2 + n] : 0.f;
            unsigned short hi = bfhi(w);
            dst[i] = h ? bfhi(w - bf2f(hi)) : hi;
        }
    }
}

// One-time: q3[l][c] = w3^T G w3
__global__ __launch_bounds__(128) void k_quad(const float* __restrict__ G,
                                              const float* __restrict__ convW,
                                              float* __restrict__ q3){
    int l = blockIdx.x, c = threadIdx.x;
    const float* Wl = convW + (size_t)l * 169 * C2;
    __shared__ float GL[Kc * Kc];
    for (int i = c; i < Kc * Kc; i += 128) GL[i] = G[i];
    float w3[Kc];
    #pragma unroll
    for (int k = 0; k < Kc; ++k) w3[k] = Wl[(C2 + k) * C2 + c];
    __syncthreads();
    float q = 0.f;
    for (int k = 0; k < Kc; ++k){
        float gw = 0.f;
        #pragma unroll
        for (int m = 0; m < Kc; ++m) gw += GL[k * Kc + m] * w3[m];
        q += w3[k] * gw;
    }
    q3[l * C2 + c] = q;
}

// Fused: [BN2-update of previous layer] + p12 + closed-form BN1 stats.
// (identical to R12)
__global__ __launch_bounds__(128)
void k_front(float* __restrict__ fea,
             const float* __restrict__ Wl,
             const float* __restrict__ bl,
             const float* __restrict__ W3Tl,
             const float* __restrict__ ST,
             const float* __restrict__ cntf,
             float* __restrict__ p1,
             float* __restrict__ p2,
             float* __restrict__ sum1R,
             float* __restrict__ sq1R,
             const float* __restrict__ summed,
             const float* __restrict__ sum2Rp,
             const float* __restrict__ sq2Rp,
             const float* __restrict__ g2p,
             const float* __restrict__ b2p,
             int upd){
    int c  = threadIdx.x;
    int r0 = blockIdx.x * 2;
    __shared__ float F2[2][Fc];
    __shared__ float A2L[Fc], B2L[Fc];

    if (upd){
        if (c < Fc){
            float s = 0.f, q = 0.f;
            for (int rr = 0; rr < NREP; ++rr){
                s += sum2Rp[rr * Fc + c];
                q += sq2Rp[rr * Fc + c];
            }
            float m = s * INV2;
            float v = q * INV2 - m * m;
            float A = g2p[c] * rsqrtf(v + EPSBN);
            A2L[c] = A;
            B2L[c] = b2p[c] - m * A;
        }
        __syncthreads();
        {
            int rr = c >> 6, cc = c & 63;
            int r  = r0 + rr;
            float nv = sp_(fea[r * Fc + cc] + summed[r * Fc + cc] * A2L[cc] + B2L[cc]);
            F2[rr][cc] = nv;
            fea[r * Fc + cc] = nv;
        }
        __syncthreads();
    } else {
        int rr = c >> 6, cc = c & 63;
        F2[rr][cc] = fea[(r0 + rr) * Fc + cc];
        __syncthreads();
    }

    float w3[Kc];
    const float* wt = W3Tl + c * 44;
    #pragma unroll
    for (int k = 0; k < 40; k += 4){
        float4 v = *(const float4*)(wt + k);
        w3[k] = v.x; w3[k+1] = v.y; w3[k+2] = v.z; w3[k+3] = v.w;
    }
    w3[40] = wt[40];
    float s1 = 0.f, q1 = 0.f;
    for (int rr = 0; rr < 2; ++rr){
        int r = r0 + rr;
        float a1 = bl[c], a2 = 0.f;
        #pragma unroll 8
        for (int f = 0; f < Fc; ++f){
            float fv = F2[rr][f];
            a1 += fv * Wl[f * C2 + c];
            a2 += fv * Wl[(Fc + f) * C2 + c];
        }
        p1[r * C2 + c] = a1;
        p2[r * C2 + c] = a2;
        const float* Sr = ST + r * (2 * Kc);
        const float* Tr = Sr + Kc;
        float u = 0.f, tt = 0.f;
        #pragma unroll
        for (int k = 0; k < Kc; ++k){ u += Sr[k] * w3[k]; tt += Tr[k] * w3[k]; }
        float cn = cntf[r];
        s1 += (float)NAt * a1 + cn * a2 + u;
        q1 += (float)NAt * a1 * a1 + cn * a2 * a2
            + 2.f * cn * a1 * a2 + 2.f * a1 * u + 2.f * a2 * tt;
    }
    int slot = blockIdx.x & (NREP - 1);
    atomicAdd(&sum1R[slot * C2 + c], s1);
    atomicAdd(&sq1R[slot * C2 + c], q1);
}

// Pass 2 v7 (MFMA): one r per block, 512 thr = 8 waves.
// GEMM nbr(96x41) @ W3(41x128) via 16x16x32 bf16 MFMA, hi/lo split (3 passes).
// Wave w: N-pair (ntF=w&3, ntF+4), M-half mh=w>>2 (3 M-tiles).
// Layouts (guide m89/m120): A[m=lane&15][k=(lane>>4)*8+i]; B[k][n=lane&15];
// D: col=lane&15, row=(lane>>4)*4+reg.
__global__ __launch_bounds__(512)
void k_apply(const float* __restrict__ nbr,
             const int*   __restrict__ adj,
             const unsigned short* __restrict__ W3Fl,
             const float* __restrict__ p1,
             const float* __restrict__ p2,
             const float* __restrict__ sum1R,
             const float* __restrict__ sq1R,
             const float* __restrict__ qv,
             const float* __restrict__ g1,
             const float* __restrict__ b1,
             float* __restrict__ summed,
             float* __restrict__ sum2R,
             float* __restrict__ sq2R){
    int r    = blockIdx.x;
    int tid  = threadIdx.x;
    int lane = tid & 63;
    int w    = __builtin_amdgcn_readfirstlane(tid >> 6);  // wave 0..7
    int ntF  = w & 3;
    int mh   = w >> 2;

    __shared__ unsigned short sAH[NAt * AROW];   // 13824 B
    __shared__ unsigned short sAL[NAt * AROW];   // 13824 B
    __shared__ float AJ[NAt];
    __shared__ float PL1[C2], PL2[C2], A1L[C2], B1L[C2];
    __shared__ float TpW[8][16];

    // ---- stage B fragments (registers, global, no LDS dep) ----
    short8_t BH[2][2], BL[2][2];
    #pragma unroll
    for (int ni = 0; ni < 2; ++ni){
        int nt = ntF + ni * 4;
        #pragma unroll
        for (int ks = 0; ks < 2; ++ks){
            int fidH = (nt * 2 + ks) * 2;
            BH[ni][ks] = *(const short8_t*)(W3Fl + fidH * 512 + lane * 8);
            BL[ni][ks] = *(const short8_t*)(W3Fl + (fidH + 1) * 512 + lane * 8);
        }
    }

    // ---- stage A (nbr row-block) as bf16 hi/lo into LDS ----
    const float* nb = nbr + (size_t)r * (NAt * Kc);
    for (int idx = tid; idx < NAt * Kc; idx += 512){
        int j = idx / Kc, k = idx - j * Kc;
        float x = nb[idx];
        unsigned short hi = bfhi(x);
        sAH[j * AROW + k] = hi;
        sAL[j * AROW + k] = bfhi(x - bf2f(hi));
    }
    for (int idx = tid; idx < NAt * 23; idx += 512){  // zero k in [41,64)
        int j = idx / 23, k = Kc + (idx - j * 23);
        sAH[j * AROW + k] = 0;
        sAL[j * AROW + k] = 0;
    }
    // ---- stage BN1 affine, p1/p2, adj ----
    if (tid < C2){
        int c = tid;
        float s = 0.f, q = 0.f;
        for (int rr = 0; rr < NREP; ++rr){ s += sum1R[rr * C2 + c]; q += sq1R[rr * C2 + c]; }
        float m = s * INV1;
        float v = (q + qv[c]) * INV1 - m * m;
        float A = g1[c] * rsqrtf(v + EPSBN);
        A1L[c] = A;
        B1L[c] = b1[c] - m * A;
    } else if (tid < 256){
        PL1[tid - 128] = p1[r * C2 + tid - 128];
    } else if (tid < 384){
        PL2[tid - 256] = p2[r * C2 + tid - 256];
    } else if (tid < 480){
        AJ[tid - 384] = (float)adj[r * NAt + tid - 384];
    }
    __syncthreads();

    // ---- MFMA: 3 M-tiles x 2 N-tiles x 2 ksteps x 3 passes ----
    f32x4 acc[3][2] = {};
    int q4 = (lane >> 4) * 8;
    #pragma unroll
    for (int mt = 0; mt < 3; ++mt){
        int jrow = (mh * 48 + mt * 16 + (lane & 15)) * AROW;
        short8_t AH0 = *(const short8_t*)(&sAH[jrow + q4]);
        short8_t AH1 = *(const short8_t*)(&sAH[jrow + 32 + q4]);
        short8_t AL0 = *(const short8_t*)(&sAL[jrow + q4]);
        short8_t AL1 = *(const short8_t*)(&sAL[jrow + 32 + q4]);
        #pragma unroll
        for (int ni = 0; ni < 2; ++ni){
            acc[mt][ni] = __builtin_amdgcn_mfma_f32_16x16x32_bf16(AH0, BH[ni][0], acc[mt][ni], 0, 0, 0);
            acc[mt][ni] = __builtin_amdgcn_mfma_f32_16x16x32_bf16(AH0, BL[ni][0], acc[mt][ni], 0, 0, 0);
            acc[mt][ni] = __builtin_amdgcn_mfma_f32_16x16x32_bf16(AL0, BH[ni][0], acc[mt][ni], 0, 0, 0);
            acc[mt][ni] = __builtin_amdgcn_mfma_f32_16x16x32_bf16(AH1, BH[ni][1], acc[mt][ni], 0, 0, 0);
            acc[mt][ni] = __builtin_amdgcn_mfma_f32_16x16x32_bf16(AH1, BL[ni][1], acc[mt][ni], 0, 0, 0);
            acc[mt][ni] = __builtin_amdgcn_mfma_f32_16x16x32_bf16(AL1, BH[ni][1], acc[mt][ni], 0, 0, 0);
        }
    }

    // ---- epilogue: BN1 + sgm*sp + j-reduction ----
    int cF = ntF * 16 + (lane & 15);
    int cC = cF + 64;
    float p1F = PL1[cF], p2F = PL2[cF], A1F = A1L[cF], B1F = B1L[cF];
    float p1C = PL1[cC], p2C = PL2[cC], A1C = A1L[cC], B1C = B1L[cC];
    float tsum = 0.f;
    #pragma unroll
    for (int mt = 0; mt < 3; ++mt){
        #pragma unroll
        for (int rg = 0; rg < 4; ++rg){
            int j = mh * 48 + mt * 16 + (lane >> 4) * 4 + rg;
            float ajf = AJ[j];                       // 16-lane broadcast
            float gf = (p1F + ajf * p2F + acc[mt][0][rg]) * A1F + B1F;
            float gc = (p1C + ajf * p2C + acc[mt][1][rg]) * A1C + B1C;
            tsum += sgm_(gf) * sp_(gc);
        }
    }
    tsum += __shfl_xor(tsum, 16);
    tsum += __shfl_xor(tsum, 32);
    if (lane < 16) TpW[w][lane] = tsum;
    __syncthreads();
    if (tid < Fc){
        int f = tid;
        float s = TpW[f >> 4][f & 15] + TpW[(f >> 4) + 4][f & 15];
        summed[r * Fc + f] = s;
        int slot = blockIdx.x & (NREP - 1);
        atomicAdd(&sum2R[slot * Fc + f], s);
        atomicAdd(&sq2R[slot * Fc + f], s * s);
    }
}

// Tail: apply layer-2 BN2 update inline, mean over i, fc, out.
__global__ __launch_bounds__(128) void k_final(const float* __restrict__ fea,
                                               const float* __restrict__ summed,
                                               const float* __restrict__ sum2R,
                                               const float* __restrict__ sq2R,
                                               const float* __restrict__ g2,
                                               const float* __restrict__ b2,
                                               const float* __restrict__ fcW,
                                               const float* __restrict__ fcb,
                                               const float* __restrict__ outW,
                                               const float* __restrict__ outb,
                                               float* __restrict__ out){
    int b = blockIdx.x;
    int t = threadIdx.x;
    __shared__ float spc[Fc];
    __shared__ float red[Hc];
    if (t < Fc){
        float s = 0.f, q = 0.f;
        for (int r = 0; r < NREP; ++r){ s += sum2R[r * Fc + t]; q += sq2R[r * Fc + t]; }
        float m  = s * INV2;
        float v  = q * INV2 - m * m;
        float A2 = g2[t] * rsqrtf(v + EPSBN);
        float B2 = b2[t] - m * A2;
        float acc = 0.f;
        for (int i = 0; i < NAt; ++i){
            int idx = (b * NAt + i) * Fc + t;
            acc += sp_(fea[idx] + summed[idx] * A2 + B2);
        }
        spc[t] = sp_(acc * (1.f / NAt));
    }
    __syncthreads();
    float h = fcb[t];
    #pragma unroll 4
    for (int f = 0; f < Fc; ++f) h += spc[f] * fcW[f * Hc + t];
    h = sp_(h);
    red[t] = h * outW[t];
    __syncthreads();
    for (int off = 64; off > 0; off >>= 1){
        if (t < off) red[t] += red[t + off];
        __syncthreads();
    }
    if (t == 0) out[b] = red[0] + outb[0];
}

extern "C" void kernel_launch(void* const* d_in, const int* in_sizes, int n_in,
                              void* d_out, int out_size, void* d_ws, size_t ws_size,
                              hipStream_t stream){
    const float* atom  = (const float*)d_in[0];
    const float* nbr   = (const float*)d_in[1];
    const int*   adj   = (const int*)  d_in[2];
    const float* embW  = (const float*)d_in[3];
    const float* embB  = (const float*)d_in[4];
    const float* convW = (const float*)d_in[5];
    const float* convB = (const float*)d_in[6];
    const float* bn1g  = (const float*)d_in[7];
    const float* bn1b  = (const float*)d_in[8];
    const float* bn2g  = (const float*)d_in[9];
    const float* bn2b  = (const float*)d_in[10];
    const float* fcW   = (const float*)d_in[11];
    const float* fcb   = (const float*)d_in[12];
    const float* outW  = (const float*)d_in[13];
    const float* outb  = (const float*)d_in[14];
    float* out = (float*)d_out;
    float* ws  = (float*)d_ws;

    const int ROWS = N0c * NAt;            // 1536
    float* fea    = ws;                    // 98304
    float* p1     = ws + 98304;            // 196608
    float* p2     = ws + 294912;           // 196608
    float* summed = ws + 491520;           // 98304
    float* SRL    = ws + 589824;           // 3 * 12288
    float* ST     = ws + 626688;           // 125952
    float* cntf   = ws + 752640;           // 1536
    float* q3     = ws + 754176;           // 384
    float* W3T    = ws + 754560;           // 16896
    unsigned short* W3F = (unsigned short*)(ws + 771456);  // 3*16384 us = 24576 f
    const size_t PERS = 796032;

    size_t ws_f = ws_size / sizeof(float);
    int nblk; float *pG, *G;
    if (ws_f >= PERS + (size_t)1536 * 1681 + 1681 + 64){
        nblk = 1536; pG = ws + PERS; G = pG + (size_t)nblk * 1681;
    } else if (ws_f >= PERS + (size_t)768 * 1681 + 1681 + 64){
        nblk = 768;  pG = ws + PERS; G = pG + (size_t)nblk * 1681;
    } else if (ws_f >= PERS + (size_t)384 * 1681 + 1681 + 64){
        nblk = 384;  pG = ws + PERS; G = pG + (size_t)nblk * 1681;
    } else {
        // compact overlay: pG over fea..SRL (dead until k_embed); G inside ST
        // (written by k_pre AFTER k_quad consumed G).
        nblk = 384;  pG = ws;        G = ws + 650000;
    }
    int rpb = 1536 / nblk;
    int ph  = nblk / 96;

    hipMemsetAsync(G, 0, Kc * Kc * sizeof(float), stream);
    k_gram <<<nblk, 128, 0, stream>>>(nbr, pG, rpb);
    k_gred <<<27 * ph, 64, 0, stream>>>(pG, G);
    k_wt   <<<NCc, C2, 0, stream>>>(convW, W3T);
    k_wtb  <<<NCc, 256, 0, stream>>>(convW, W3F);
    k_quad <<<NCc, C2, 0, stream>>>(G, convW, q3);
    k_embed<<<ROWS / 4, 256, 0, stream>>>(atom, embW, embB, fea);
    k_pre  <<<ROWS, 256, 0, stream>>>(nbr, adj, ST, cntf);
    hipMemsetAsync(SRL, 0, 3 * SRL_STRIDE * sizeof(float), stream);

    for (int l = 0; l < NCc; ++l){
        const float* Wl   = convW + (size_t)l * 169 * C2;
        const float* bl   = convB + l * C2;
        const float* W3Tl = W3T + (size_t)l * C2 * 44;
        const unsigned short* W3Fl = W3F + (size_t)l * WFRAG;
        float* sum1R = SRL + l * SRL_STRIDE;
        float* sq1R  = sum1R + 4096;
        float* sum2R = sum1R + 8192;
        float* sq2R  = sum1R + 10240;
        const float* sum2Rp = (l > 0) ? SRL + (l - 1) * SRL_STRIDE + 8192 : SRL;
        const float* sq2Rp  = (l > 0) ? SRL + (l - 1) * SRL_STRIDE + 10240 : SRL;
        const float* g2p    = bn2g + (l > 0 ? (l - 1) : 0) * Fc;
        const float* b2p    = bn2b + (l > 0 ? (l - 1) : 0) * Fc;

        k_front <<<ROWS / 2, C2, 0, stream>>>(fea, Wl, bl, W3Tl, ST, cntf,
                                              p1, p2, sum1R, sq1R,
                                              summed, sum2Rp, sq2Rp, g2p, b2p,
                                              l > 0 ? 1 : 0);
        k_apply <<<ROWS, 512, 0, stream>>>(nbr, adj, W3Fl, p1, p2,
                                           sum1R, sq1R, q3 + l * C2,
                                           bn1g + l * C2, bn1b + l * C2,
                                           summed, sum2R, sq2R);
    }

    k_final<<<N0c, Hc, 0, stream>>>(fea, summed,
                                    SRL + 2 * SRL_STRIDE + 8192,
                                    SRL + 2 * SRL_STRIDE + 10240,
                                    bn2g + 2 * Fc, bn2b + 2 * Fc,
                                    fcW, fcb, outW, outb, out);
}